// Round 1
// 93.447 us; speedup vs baseline: 1.0454x; 1.0454x over previous
//
#include <hip/hip_runtime.h>
#include <hip/hip_bf16.h>

#define EPSW 1e-6f

typedef __attribute__((ext_vector_type(4))) float floatx4;
typedef __attribute__((ext_vector_type(4))) unsigned int uintx4;
typedef __attribute__((ext_vector_type(8))) short shortx8;   // 8 bf16 (4 VGPRs)

// round-to-nearest-even float -> bf16 bits (finite inputs)
__device__ __forceinline__ unsigned short f2bf(float f) {
    unsigned int u = __float_as_uint(f);
    u = (u + 0x7fffu + ((u >> 16) & 1u)) >> 16;
    return (unsigned short)u;
}

__device__ __forceinline__ unsigned int pk2(float lo, float hi) {
    return (unsigned int)f2bf(lo) | ((unsigned int)f2bf(hi) << 16);
}

// async global->LDS DMA, 16B per lane: lane i's 16B land at l + i*16.
__device__ __forceinline__ void gl_lds16(const void* g, void* l) {
    __builtin_amdgcn_global_load_lds(
        (const __attribute__((address_space(1))) unsigned int*)g,
        (__attribute__((address_space(3))) unsigned int*)l, 16, 0, 0);
}

// ---------------------------------------------------------------------------
// prep: 20 blocks x 512 threads.
//   blocks 0..15 : W -> wt bf16, granule (kg,h) at kg*128+h, zero-padded.
//   blocks 16..19: Mt[c][n] = (A@A)[n][c], n-sliced 16 rows per block.
//                  Each block redundantly builds A (cheap) so no cross-block
//                  dependency; inner product hoists A[k][c] so the per-wave
//                  LDS instruction count is ~3/k-step instead of ~16/k-step.
// x transpose is GONE from prep -- fused into gemm_lds A-staging.
// ---------------------------------------------------------------------------
__global__ __launch_bounds__(512) void prep(const float* __restrict__ W,
                                            const int* __restrict__ ei,
                                            const float* __restrict__ ew,
                                            unsigned short* __restrict__ wt,
                                            float* __restrict__ Mt) {
    __shared__ float sA[4096 + 128];
    const int bid = blockIdx.x;
    const int t   = threadIdx.x;

    if (bid < 16) {
#pragma unroll
        for (int i = 0; i < 4; ++i) {
            const int G  = bid * 2048 + i * 512 + t;  // 0..32767
            const int kg = G >> 7;
            const int h  = G & 127;
            const int k  = kg * 8;
            floatx4 v0 = (floatx4){0.f, 0.f, 0.f, 0.f};
            floatx4 v1 = (floatx4){0.f, 0.f, 0.f, 0.f};
            if (k < 2000) {  // kg<=249 -> whole granule valid
                v0 = *(const floatx4*)(W + (size_t)h * 2000 + k);
                v1 = *(const floatx4*)(W + (size_t)h * 2000 + k + 4);
            }
            unsigned short* p = wt + ((size_t)kg * 128 + h) * 8;
            p[0] = f2bf(v0.x); p[1] = f2bf(v0.y); p[2] = f2bf(v0.z); p[3] = f2bf(v0.w);
            p[4] = f2bf(v1.x); p[5] = f2bf(v1.y); p[6] = f2bf(v1.z); p[7] = f2bf(v1.w);
        }
    } else {
        const int bb = bid - 16;                // 0..3: n-slice [bb*16, bb*16+16)
        float* A    = sA;                       // 4096 f, A[n][k] (row-major)
        float* deg  = sA + 4096;
        float* dinv = deg + 64;
        if (t < 64) deg[t] = 1.0f;              // self-loop pre-added
        for (int i = t; i < 4096; i += 512) A[i] = 0.0f;
        __syncthreads();
        const int* srcp = ei;
        const int* dstp = ei + 4096;
#pragma unroll
        for (int i = 0; i < 8; ++i) {
            const int e = i * 512 + t;
            float w = ew[e];
            w = (w <= 0.0f) ? EPSW : w;
            atomicAdd(&deg[dstp[e]], w);
        }
        __syncthreads();
        if (t < 64) dinv[t] = 1.0f / sqrtf(deg[t]);
        __syncthreads();
#pragma unroll
        for (int i = 0; i < 8; ++i) {
            const int e = i * 512 + t;
            float w = ew[e];
            w = (w <= 0.0f) ? EPSW : w;
            const int s = srcp[e], d = dstp[e];
            atomicAdd(&A[d * 64 + s], dinv[s] * w * dinv[d]);
        }
        if (t < 64) atomicAdd(&A[t * 64 + t], dinv[t] * dinv[t]);
        __syncthreads();
        // outputs: c = t&63 (lane-varying, conflict-free reads of A[k][c]);
        // n0,n1 wave-uniform (broadcast reads of A[n][k]).
        const int c  = t & 63;
        const int n0 = bb * 16 + (t >> 6);
        const int n1 = n0 + 8;
        float s0 = 0.0f, s1 = 0.0f;
#pragma unroll 8
        for (int k = 0; k < 64; ++k) {
            const float akc = A[k * 64 + c];
            s0 += A[n0 * 64 + k] * akc;
            s1 += A[n1 * 64 + k] * akc;
        }
        Mt[c * 64 + n0] = s0;
        Mt[c * 64 + n1] = s1;
    }
}

// ---------------------------------------------------------------------------
// gemm_lds: 256 blocks x 256 threads (4 waves). Block bid: ks = bid>>5
// (K-slice of 256 = 32 kg), rbase = (bid&31)*64.
// A-path (NEW): fused transpose+cvt. Per chunk (BK=64 = 8 kg) each thread
// reg-stages 2 granules of x fp32 (2x32B, 8-lane groups read contiguous
// 256B row segments), converts to bf16, ds_write_b128 into the granule
// layout sbA[kgl][row] (lanes 0..7 -> consecutive rows -> conflict-free
// write phases). A-loads for chunk c+1 issue before compute of chunk c.
// B-path: unchanged async global_load_lds width-16 from wt.
// LDS per buf: A 8 kg x 64 rows x 16B = 8 KB | B 8 kg x 128 h x 16B = 16 KB.
// Compute: wave w owns h-tiles {w, w+4}: acc[rt 0..3][hh 0..1]; per chunk
// 2 k-quads x (4 A + 2 B ds_read_b128, 8 MFMA) = 16 MFMA.
// Epilogue: partials to zp[ks][row][h] (unique owner, plain stores).
// ---------------------------------------------------------------------------
__global__ __launch_bounds__(256) void gemm_lds(
        const float* __restrict__ x,
        const unsigned short* __restrict__ wt,
        float* __restrict__ zp) {
    __shared__ __align__(16) unsigned char smem[2][24576];
    const int t    = threadIdx.x;
    const int wave = t >> 6, lane = t & 63;
    const int m = lane & 15, q = lane >> 4;
    const int bid   = blockIdx.x;
    const int ks    = bid >> 5;         // 0..7
    const int rbase = (bid & 31) * 64;  // 0..1984
    const int kg0   = ks * 32;

    const int kgl = lane >> 3;               // 0..7  A-staging granule col
    const int rr0 = wave * 8 + (lane & 7);   // A-staging row (i=0); +32 for i=1

    floatx4 acc[4][2];
#pragma unroll
    for (int rt = 0; rt < 4; ++rt)
#pragma unroll
        for (int hh = 0; hh < 2; ++hh)
            acc[rt][hh] = (floatx4){0.f, 0.f, 0.f, 0.f};

    floatx4 va0, va1, vb0, vb1;  // staged x: rows rr0 / rr0+32, 8 k each

#define LOAD_A(c)                                                             \
    {                                                                         \
        const int k_ = ks * 256 + (c) * 64 + kgl * 8;                         \
        const float* px_ = x + (size_t)(rbase + rr0) * 2000 + k_;             \
        if (k_ < 2000) {                                                      \
            va0 = *(const floatx4*)px_;                                       \
            va1 = *(const floatx4*)(px_ + 4);                                 \
            vb0 = *(const floatx4*)(px_ + 64000);                             \
            vb1 = *(const floatx4*)(px_ + 64004);                             \
        } else {                                                              \
            va0 = va1 = vb0 = vb1 = (floatx4){0.f, 0.f, 0.f, 0.f};            \
        }                                                                     \
    }

#define WRITE_A(c)                                                            \
    {                                                                         \
        unsigned char* sb_ = smem[(c) & 1];                                   \
        uintx4 g0_, g1_;                                                      \
        g0_.x = pk2(va0.x, va0.y); g0_.y = pk2(va0.z, va0.w);                 \
        g0_.z = pk2(va1.x, va1.y); g0_.w = pk2(va1.z, va1.w);                 \
        g1_.x = pk2(vb0.x, vb0.y); g1_.y = pk2(vb0.z, vb0.w);                 \
        g1_.z = pk2(vb1.x, vb1.y); g1_.w = pk2(vb1.z, vb1.w);                 \
        *(uintx4*)(sb_ + kgl * 1024 + rr0 * 16) = g0_;                        \
        *(uintx4*)(sb_ + kgl * 1024 + (rr0 + 32) * 16) = g1_;                 \
    }

#define ISSUE_B(c)                                                            \
    {                                                                         \
        unsigned char* sb_ = smem[(c) & 1];                                   \
        const int ckg_ = kg0 + (c) * 8;                                       \
        for (int j = wave; j < 16; j += 4) {                                  \
            const int kb_ = j >> 1, hf_ = j & 1;                              \
            gl_lds16(wt + ((size_t)(ckg_ + kb_) * 128 + hf_ * 64 + lane) * 8, \
                     sb_ + 8192 + kb_ * 2048 + hf_ * 1024);                   \
        }                                                                     \
    }

    LOAD_A(0);
    ISSUE_B(0);
    for (int c = 0; c < 4; ++c) {
        __builtin_amdgcn_s_waitcnt(0);   // own A regs + B DMA drained
        WRITE_A(c);                      // bf16 granules into buf c&1
        if (c < 3) {                     // overlap next chunk's HBM latency
            LOAD_A(c + 1);
            ISSUE_B(c + 1);
        }
        __syncthreads();                 // all waves' A writes + B DMA published
        const unsigned char* sb = smem[c & 1];
#pragma unroll
        for (int p = 0; p < 2; ++p) {
            // A-frags: granule (kgq = p*4+q, row = rt*16+m)
            shortx8 a[4];
#pragma unroll
            for (int rt = 0; rt < 4; ++rt)
                a[rt] = *(const shortx8*)(sb + (p * 4 + q) * 1024 + (rt * 16 + m) * 16);
            // B-frags: granule (kgq, h = (wave+hh*4)*16+m)
            shortx8 bb[2];
#pragma unroll
            for (int hh = 0; hh < 2; ++hh)
                bb[hh] = *(const shortx8*)(sb + 8192 + (p * 4 + q) * 2048 +
                                           ((wave + hh * 4) * 16 + m) * 16);
#pragma unroll
            for (int rt = 0; rt < 4; ++rt)
#pragma unroll
                for (int hh = 0; hh < 2; ++hh)
                    acc[rt][hh] = __builtin_amdgcn_mfma_f32_16x16x32_bf16(
                        a[rt], bb[hh], acc[rt][hh], 0, 0, 0);
        }
        __syncthreads();                 // all reads of buf c done before reuse
    }
#undef LOAD_A
#undef WRITE_A
#undef ISSUE_B

    // epilogue: partial z. C/D layout: row = q*4+v, col = m.
#pragma unroll
    for (int rt = 0; rt < 4; ++rt)
#pragma unroll
        for (int hh = 0; hh < 2; ++hh) {
            const int h = (wave + hh * 4) * 16 + m;
#pragma unroll
            for (int v = 0; v < 4; ++v) {
                const int row = rbase + rt * 16 + q * 4 + v;
                zp[((size_t)ks * 2048 + row) * 128 + h] = acc[rt][hh][v];
            }
        }
}

// ---------------------------------------------------------------------------
// apply_M: y[b][n][h] = bias[h] + sum_m M[n][m] * (sum_ks zp[ks][b*64+m][h])
// Grid (32 b, 8 h-chunks of 16) x 256 thr (r13-validated).
// ---------------------------------------------------------------------------
__global__ __launch_bounds__(256) void apply_M(const float* __restrict__ zp,
                                               const float* __restrict__ Mtg,
                                               const float* __restrict__ bias,
                                               float* __restrict__ y) {
    __shared__ float Ms[4096];
    __shared__ float zs[64][16];
    const int b  = blockIdx.x;
    const int hc = blockIdx.y;
    const int t  = threadIdx.x;
#pragma unroll
    for (int i = 0; i < 16; ++i) Ms[i * 256 + t] = Mtg[i * 256 + t];
#pragma unroll
    for (int i = 0; i < 4; ++i) {
        const int idx = i * 256 + t;
        const int mr = idx >> 4, hh = idx & 15;
        float s = 0.0f;
#pragma unroll
        for (int ks = 0; ks < 8; ++ks)
            s += zp[((size_t)ks * 2048 + b * 64 + mr) * 128 + hc * 16 + hh];
        zs[mr][hh] = s;
    }
    __syncthreads();
    const int h  = t & 15;
    const int n0 = (t >> 4) * 4;
    const float bv = bias[hc * 16 + h];
    float s0 = bv, s1 = bv, s2 = bv, s3 = bv;
#pragma unroll
    for (int mm = 0; mm < 64; ++mm) {
        const float zv = zs[mm][h];
        s0 += Ms[mm * 64 + n0 + 0] * zv;
        s1 += Ms[mm * 64 + n0 + 1] * zv;
        s2 += Ms[mm * 64 + n0 + 2] * zv;
        s3 += Ms[mm * 64 + n0 + 3] * zv;
    }
    float* yp = y + (size_t)b * 8192 + (size_t)n0 * 128 + hc * 16 + h;
    yp[0]   = s0;
    yp[128] = s1;
    yp[256] = s2;
    yp[384] = s3;
}

extern "C" void kernel_launch(void* const* d_in, const int* in_sizes, int n_in,
                              void* d_out, int out_size, void* d_ws, size_t ws_size,
                              hipStream_t stream) {
    const float* x    = (const float*)d_in[0];   // (2048, 2000) fp32 (flat view)
    const int*   ei   = (const int*)d_in[1];     // (2, 4096)
    const float* ew   = (const float*)d_in[2];   // (4096,)
    const float* W    = (const float*)d_in[3];   // (128, 2000) fp32
    const float* bias = (const float*)d_in[4];   // (128,)
    float* y = (float*)d_out;                    // (32, 64, 128) fp32

    float* zp = (float*)d_ws;                            // 8*2048*128 f (8 MB)
    float* Mt = zp + 2097152;                            // 4096 f
    unsigned short* wt = (unsigned short*)(Mt + 4096);   // 256*128*8 bf16 (512 KB)

    prep<<<20, 512, 0, stream>>>(W, ei, ew, wt, Mt);
    gemm_lds<<<256, 256, 0, stream>>>(x, wt, zp);
    apply_M<<<dim3(32, 8), 256, 0, stream>>>(zp, Mt, bias, y);
}